// Round 1
// baseline (202.808 us; speedup 1.0000x reference)
//
#include <hip/hip_runtime.h>
#include <math.h>

#define BATCH 32
#define HW (512*512)
#define TILE 256
#define NTILES (HW / TILE)   // 1024
#define GRID1 512            // 2 tiles per block

// ws layout (floats): [0..1023] G[32][32], [1024] N1[32], [1056] N2[32],
// [1088] PP[32], [1120] P1[32], [1152] P2[32]  -> 1184 floats total

__device__ __forceinline__ float fsigmoid(float x) {
    float e = __builtin_amdgcn_exp2f(-x * 1.44269504088896340736f);
    return __builtin_amdgcn_rcpf(1.0f + e);
}

// Swizzled column: conflict-free for phase A writes, phase B float4 reads,
// and ~2-way for phase C reads. XOR touches only bits >=2, so 16B alignment
// of 4-aligned p is preserved.
__device__ __forceinline__ int swcol(int b, int p) {
    return p ^ (((b >> 2) << 2) ^ ((b & 3) << 3));
}

__global__ __launch_bounds__(256) void cos_loss_main(
    const float* __restrict__ x1, const float* __restrict__ x2,
    const float* __restrict__ mk, float* __restrict__ ws)
{
    __shared__ float s1q[BATCH * TILE];
    __shared__ float s2q[BATCH * TILE];

    const int t    = threadIdx.x;
    const int w    = t >> 6;        // wave 0..3
    const int lane = t & 63;
    const int bi   = lane >> 3;     // 0..7  (row block of 4)
    const int di   = lane & 7;      // 0..7  (col block of 4)
    const int cb   = t >> 3;        // phase C batch 0..31
    const int cp0  = t & 7;         // phase C position slot

    float acc[4][4];
    #pragma unroll
    for (int i = 0; i < 4; ++i)
        #pragma unroll
        for (int j = 0; j < 4; ++j) acc[i][j] = 0.f;

    float app = 0.f, ap1 = 0.f, ap2 = 0.f, an1 = 0.f, an2 = 0.f;

    for (int tile = blockIdx.x; tile < NTILES; tile += GRID1) {
        const int base = tile * TILE;
        __syncthreads();   // prev-iter LDS readers done before overwrite

        // ---- Phase A: global -> sigmoid^2 -> LDS (swizzled), coalesced per b
        #pragma unroll 8
        for (int b = 0; b < BATCH; ++b) {
            unsigned idx = (unsigned)b * HW + base + t;
            float s1 = fsigmoid(x1[idx]);
            float s2 = fsigmoid(x2[idx]);
            int col = swcol(b, t);
            s1q[b * TILE + col] = s1 * s1;
            s2q[b * TILE + col] = s2 * s2;
        }
        __syncthreads();

        // ---- Phase B: Gram accumulation. Wave w covers positions [64w,64w+64).
        const int p0 = w * 64;
        #pragma unroll
        for (int ps = 0; ps < 64; ps += 4) {
            int p = p0 + ps;
            float4 av[4], bv[4];
            #pragma unroll
            for (int i = 0; i < 4; ++i) {
                int br = bi * 4 + i;
                av[i] = *(const float4*)&s1q[br * TILE + swcol(br, p)];
                int dr = di * 4 + i;
                bv[i] = *(const float4*)&s2q[dr * TILE + swcol(dr, p)];
            }
            #pragma unroll
            for (int i = 0; i < 4; ++i)
                #pragma unroll
                for (int j = 0; j < 4; ++j) {
                    acc[i][j] = fmaf(av[i].x, bv[j].x, acc[i][j]);
                    acc[i][j] = fmaf(av[i].y, bv[j].y, acc[i][j]);
                    acc[i][j] = fmaf(av[i].z, bv[j].z, acc[i][j]);
                    acc[i][j] = fmaf(av[i].w, bv[j].w, acc[i][j]);
                }
        }

        // ---- Phase C: per-batch masked sums; mask from global (L2-hot),
        //      s1q/s2q from LDS. Thread t handles batch cb, positions cp0+8k.
        {
            unsigned mbase = (unsigned)cb * HW + base;
            #pragma unroll 8
            for (int k = 0; k < TILE / 8; ++k) {
                int p = cp0 + k * 8;
                float m = mk[mbase + p];
                int col = swcol(cb, p);
                float q1 = s1q[cb * TILE + col];
                float q2 = s2q[cb * TILE + col];
                an1 += q1;
                an2 += q2;
                app = fmaf(m, q1 * q2, app);
                ap1 = fmaf(m, q1, ap1);
                ap2 = fmaf(m, q2, ap2);
            }
        }
    }

    // ---- flush phase C partials: 8 consecutive lanes share one cb
    #pragma unroll
    for (int off = 1; off < 8; off <<= 1) {
        an1 += __shfl_xor(an1, off);
        an2 += __shfl_xor(an2, off);
        app += __shfl_xor(app, off);
        ap1 += __shfl_xor(ap1, off);
        ap2 += __shfl_xor(ap2, off);
    }
    if (cp0 == 0) {
        atomicAdd(&ws[1024 + cb], an1);
        atomicAdd(&ws[1056 + cb], an2);
        atomicAdd(&ws[1088 + cb], app);
        atomicAdd(&ws[1120 + cb], ap1);
        atomicAdd(&ws[1152 + cb], ap2);
    }

    // ---- flush Gram: merge 4 waves via LDS atomics, then global atomics
    __syncthreads();
    float* Gl = s1q;   // reuse
    Gl[t] = 0.f; Gl[t + 256] = 0.f; Gl[t + 512] = 0.f; Gl[t + 768] = 0.f;
    __syncthreads();
    #pragma unroll
    for (int i = 0; i < 4; ++i)
        #pragma unroll
        for (int j = 0; j < 4; ++j)
            atomicAdd(&Gl[(bi * 4 + i) * BATCH + (di * 4 + j)], acc[i][j]);
    __syncthreads();
    #pragma unroll
    for (int r = 0; r < 4; ++r)
        atomicAdd(&ws[t + r * 256], Gl[t + r * 256]);
}

__global__ __launch_bounds__(1024) void cos_loss_finalize(
    const float* __restrict__ ws, float* __restrict__ out)
{
    __shared__ float sn[BATCH];
    __shared__ float sp[BATCH];
    __shared__ float red[16];

    const int t = threadIdx.x;        // 0..1023
    const int b = t >> 5, d = t & 31;

    const float* G  = ws;
    const float* N1 = ws + 1024;
    const float* N2 = ws + 1056;
    const float* PP = ws + 1088;
    const float* P1 = ws + 1120;
    const float* P2 = ws + 1152;

    // sim[b][d], zero on diagonal
    float sim = 0.f;
    if (b != d) sim = sqrtf(G[t]) / (sqrtf(N1[b]) * sqrtf(N2[d]));
    // reduce across the 32 d-lanes (b constant within each 32-lane half)
    #pragma unroll
    for (int off = 1; off < 32; off <<= 1) sim += __shfl_xor(sim, off);
    if (d == 0) sn[b] = sim;
    if (t < BATCH) sp[t] = sqrtf(PP[t]) / (sqrtf(P1[t]) * sqrtf(P2[t]));
    __syncthreads();

    // loss[i][j] with i=b, j=d; mean over 1024 entries
    float spj = sp[d], sni = sn[b];
    float loss = -logf(spj / (spj + sni));
    #pragma unroll
    for (int off = 1; off < 64; off <<= 1) loss += __shfl_xor(loss, off);
    if ((t & 63) == 0) red[t >> 6] = loss;
    __syncthreads();
    if (t < 16) {
        float v = red[t];
        #pragma unroll
        for (int off = 1; off < 16; off <<= 1) v += __shfl_xor(v, off);
        if (t == 0) out[0] = v * (1.0f / 1024.0f);
    }
}

extern "C" void kernel_launch(void* const* d_in, const int* in_sizes, int n_in,
                              void* d_out, int out_size, void* d_ws, size_t ws_size,
                              hipStream_t stream)
{
    const float* x1 = (const float*)d_in[0];
    const float* x2 = (const float*)d_in[1];
    const float* mk = (const float*)d_in[2];
    float* out = (float*)d_out;
    float* ws  = (float*)d_ws;

    hipMemsetAsync(ws, 0, 1184 * sizeof(float), stream);
    cos_loss_main<<<GRID1, 256, 0, stream>>>(x1, x2, mk, ws);
    cos_loss_finalize<<<1, 1024, 0, stream>>>(ws, out);
}